// Round 7
// baseline (1615.674 us; speedup 1.0000x reference)
//
#include <hip/hip_runtime.h>

#define NGRAPH 1000
#define P      100
#define EPG    1200
#define INF    16
#define HID    64
#define NOUT   5

#define ASTR   68    // A row stride in floats (17 granules, odd -> bank spread)
#define TSTR   12    // T1/T2 row stride in floats (3 granules, odd)

// LDS: A 100*68*4=27200 + T1/T2 2*100*12*4=9600 + csr_src 2400 + csr_off 404
//      + cnt 400 + sdinv 400 = 40,404 B -> 40,448 rounded -> 4 blocks/CU

__device__ __forceinline__ void fma4(float4& a, float s, const float4 w) {
    a.x += s * w.x; a.y += s * w.y; a.z += s * w.z; a.w += s * w.w;
}

// Gather one 8-column slice D[n][0..8) for all n from CSR. Thread: q=tid&1
// (col quad within slice), n=tid>>1 (node), single pass (128 slots >= 100).
// isX2=0: D = -dinv[n] * sum_e dinv[s]*S[s]            (X1 = -Ax(X0))
// isX2=1: D = -2*dinv[n]*sum_e dinv[s]*S[s] - A0[n]    (X2 = -2Ax(X1) - X0)
__device__ __forceinline__ void prop8(
    const float* __restrict__ S, int sstride, int soff,
    float* __restrict__ D,
    const float* __restrict__ A0, int aoff, int isX2,
    const unsigned short* __restrict__ csr_src,
    const int* __restrict__ csr_off,
    const float* __restrict__ sdinv,
    int tid)
{
    const int q = tid & 1;
    const int n = tid >> 1;
    if (n < P) {
        int kb = csr_off[n], ke = csr_off[n + 1];
        float ax = 0.f, ay = 0.f, az = 0.f, aw = 0.f;
        for (int k = kb; k < ke; k++) {
            int s = csr_src[k];
            float ws = sdinv[s];
            const float4 x = *(const float4*)&S[s * sstride + soff + q * 4];
            ax += ws * x.x; ay += ws * x.y; az += ws * x.z; aw += ws * x.w;
        }
        float dn = sdinv[n];
        float4 o;
        if (!isX2) {
            float m = -dn;
            o.x = m * ax; o.y = m * ay; o.z = m * az; o.w = m * aw;
        } else {
            float m = -2.f * dn;
            const float4 x0 = *(const float4*)&A0[n * ASTR + aoff + q * 4];
            o.x = m * ax - x0.x; o.y = m * ay - x0.y;
            o.z = m * az - x0.z; o.w = m * aw - x0.w;
        }
        *(float4*)&D[n * TSTR + q * 4] = o;
    }
}

// One ChebConv(K=3) layer: A (stride ASTR, F cols) -> relu([X0|X1|X2]@W + b) -> A
// Matmul thread: cq4=(tid&15)*4 output cols; node group ng=tid>>4 (uneven:
// wave 0 -> 4 groups of 7 nodes, waves 1-3 -> 12 groups of 6; nn wave-uniform).
// IMPORTANT: acc loops are #pragma unroll with compile-time indices + uniform
// guard (i < nn) — a runtime trip count demotes acc[] to scratch (round-6 bug:
// 1.58 GB of scratch writes, 3.3x regression).
template <int F>
__device__ __forceinline__ void cheb_layer(
    float* __restrict__ A, float* __restrict__ T1, float* __restrict__ T2,
    const unsigned short* __restrict__ csr_src,
    const int* __restrict__ csr_off,
    const float* __restrict__ sdinv,
    const float* __restrict__ W, const float* __restrict__ bias,
    int tid)
{
    const int cq4 = (tid & 15) * 4;
    const int ng  = tid >> 4;
    const int n0  = (ng < 4) ? 7 * ng : 28 + 6 * (ng - 4);
    const int nn  = (ng < 4) ? 7 : 6;          // wave-uniform

    float4 acc[7];
    const float4 bv = *(const float4*)&bias[cq4];
#pragma unroll
    for (int i = 0; i < 7; i++) acc[i] = bv;

    for (int cb = 0; cb < F; cb += 8) {
        prop8(A, ASTR, cb, T1, (const float*)0, 0, 0, csr_src, csr_off, sdinv, tid);
        __syncthreads();
        prop8(T1, TSTR, 0, T2, A, cb, 1, csr_src, csr_off, sdinv, tid);
        __syncthreads();

        // partial matmul over this 8-feature slice, 3 sections (X0, X1, X2)
        for (int sec = 0; sec < 3; sec++) {
            const float* xp; int xstr, xoff, wrow0;
            if (sec == 0)      { xp = A;  xstr = ASTR; xoff = cb; wrow0 = cb; }
            else if (sec == 1) { xp = T1; xstr = TSTR; xoff = 0;  wrow0 = F + cb; }
            else               { xp = T2; xstr = TSTR; xoff = 0;  wrow0 = 2 * F + cb; }
            for (int j4 = 0; j4 < 8; j4 += 4) {
                const float4 w0 = *(const float4*)&W[(wrow0 + j4 + 0) * HID + cq4];
                const float4 w1 = *(const float4*)&W[(wrow0 + j4 + 1) * HID + cq4];
                const float4 w2 = *(const float4*)&W[(wrow0 + j4 + 2) * HID + cq4];
                const float4 w3 = *(const float4*)&W[(wrow0 + j4 + 3) * HID + cq4];
                const float* xb = xp + n0 * xstr + xoff + j4;
#pragma unroll
                for (int i = 0; i < 7; i++) {
                    if (i < nn) {
                        const float4 x = *(const float4*)&xb[i * xstr];
                        fma4(acc[i], x.x, w0); fma4(acc[i], x.y, w1);
                        fma4(acc[i], x.z, w2); fma4(acc[i], x.w, w3);
                    }
                }
            }
        }
        __syncthreads();   // T1/T2 (and A-slice) reads done before next overwrite
    }

    // H = relu(acc) -> A
#pragma unroll
    for (int i = 0; i < 7; i++) {
        if (i < nn) {
            float4 o;
            o.x = fmaxf(acc[i].x, 0.f); o.y = fmaxf(acc[i].y, 0.f);
            o.z = fmaxf(acc[i].z, 0.f); o.w = fmaxf(acc[i].w, 0.f);
            *(float4*)&A[(n0 + i) * ASTR + cq4] = o;
        }
    }
    __syncthreads();
}

__global__ __launch_bounds__(256, 4) void gnn_kernel(
    const float* __restrict__ feat,
    const int* __restrict__ src, const int* __restrict__ dst,
    const float* __restrict__ W1, const float* __restrict__ b1,
    const float* __restrict__ W2, const float* __restrict__ b2,
    const float* __restrict__ W3, const float* __restrict__ b3,
    const float* __restrict__ Wfc, const float* __restrict__ bfc,
    float* __restrict__ out)
{
    __shared__ __align__(16) float A[P * ASTR];
    __shared__ __align__(16) float T1[P * TSTR];
    __shared__ __align__(16) float T2[P * TSTR];
    __shared__ unsigned short csr_src[EPG];
    __shared__ int   csr_off[P + 1];
    __shared__ int   cnt[P];       // degree, then CSR-fill cursor
    __shared__ float sdinv[P];

    const int g = blockIdx.x;
    const int tid = threadIdx.x;
    const int base = g * P;
    const int* srcg = src + g * EPG;
    const int* dstg = dst + g * EPG;

    // ---- degree count + feat load ----
    for (int i = tid; i < P; i += 256) cnt[i] = 0;
    __syncthreads();
    for (int e = tid; e < EPG; e += 256) {
        int d = dstg[e] - base;
        atomicAdd(&cnt[d], 1);
    }
    for (int i = tid; i < P * INF / 4; i += 256) {
        int n = i >> 2, fq = (i & 3) * 4;
        *(float4*)&A[n * ASTR + fq] = *(const float4*)&feat[(size_t)base * INF + i * 4];
    }
    __syncthreads();

    for (int i = tid; i < P; i += 256) {
        int dg = cnt[i] > 1 ? cnt[i] : 1;
        sdinv[i] = rsqrtf((float)dg);
    }
    // ---- prefix scan of degrees: serial by thread 0 (P=100, negligible) ----
    if (tid == 0) {
        int run = 0;
        csr_off[0] = 0;
        for (int i = 0; i < P; i++) { run += cnt[i]; csr_off[i + 1] = run; }
    }
    __syncthreads();
    for (int i = tid; i < P; i += 256) cnt[i] = csr_off[i];   // cursor
    __syncthreads();
    // ---- CSR fill ----
    for (int e = tid; e < EPG; e += 256) {
        int s = srcg[e] - base;
        int d = dstg[e] - base;
        int pos = atomicAdd(&cnt[d], 1);
        csr_src[pos] = (unsigned short)s;
    }
    __syncthreads();

    // ---- 3 ChebConv layers ----
    cheb_layer<INF>(A, T1, T2, csr_src, csr_off, sdinv, W1, b1, tid);
    cheb_layer<HID>(A, T1, T2, csr_src, csr_off, sdinv, W2, b2, tid);
    cheb_layer<HID>(A, T1, T2, csr_src, csr_off, sdinv, W3, b3, tid);

    // ---- mean pool + FC (T1 as scratch: needs 320 floats <= 1200) ----
    {
        const int lane = tid & 63, w = tid >> 6;
        float s = 0.f;
        for (int n = w; n < P; n += 4) s += A[n * ASTR + lane];
        T1[w * 64 + lane] = s;
    }
    __syncthreads();
    if (tid < HID) {
        float hg = (T1[tid] + T1[64 + tid] + T1[128 + tid] + T1[192 + tid]) * (1.0f / P);
        T1[256 + tid] = hg;
    }
    __syncthreads();
    if (tid < NOUT) {
        float o = bfc[tid];
        for (int c = 0; c < HID; c++) o += T1[256 + c] * Wfc[c * NOUT + tid];
        out[g * NOUT + tid] = o;
    }
}

extern "C" void kernel_launch(void* const* d_in, const int* in_sizes, int n_in,
                              void* d_out, int out_size, void* d_ws, size_t ws_size,
                              hipStream_t stream)
{
    const float* feat = (const float*)d_in[0];
    const int*   src  = (const int*)d_in[1];
    const int*   dst  = (const int*)d_in[2];
    const float* W1  = (const float*)d_in[5];
    const float* b1  = (const float*)d_in[6];
    const float* W2  = (const float*)d_in[7];
    const float* b2  = (const float*)d_in[8];
    const float* W3  = (const float*)d_in[9];
    const float* b3  = (const float*)d_in[10];
    const float* Wfc = (const float*)d_in[11];
    const float* bfc = (const float*)d_in[12];
    float* out = (float*)d_out;

    gnn_kernel<<<NGRAPH, 256, 0, stream>>>(feat, src, dst,
                                           W1, b1, W2, b2, W3, b3, Wfc, bfc, out);
}

// Round 8
// 243.750 us; speedup vs baseline: 6.6284x; 6.6284x over previous
//
#include <hip/hip_runtime.h>

#define NGRAPH 1000
#define P      100
#define EPG    1200
#define INF    16
#define HID    64
#define NOUT   5

#define ASTR   68    // A row stride (17 granules, odd -> conflict-free matmul reads)
#define TSTR   8     // T1/T2 row stride = slice width
#define NPAD   112   // 16 uniform groups * 7 nodes (rows 100..111 = don't-care pad)

// LDS: A 112*68*4=30464 + T1/T2 2*112*8*4=7168 + csr_src 2400 + csr_off 404
//      + sdinv 400 = 40,836 B  -> 4 blocks/CU (4 x 40960 = 160 KiB cap)
// deg / CSR cursor are aliased onto T1 / T2 (consumed before layer 1).
//
// HARD RULE (r6/r7 lesson): every loop touching acc[] is #pragma unroll with
// compile-time trip count and NO runtime guard — anything else spills acc[]
// to HBM-backed scratch (r6: 1.6 GB, r7: 3.4 GB of scratch traffic).

__device__ __forceinline__ void fma4(float4& a, float s, const float4 w) {
    a.x += s * w.x; a.y += s * w.y; a.z += s * w.z; a.w += s * w.w;
}

// Gather one 8-column slice D[n][0..8) (n < P) from CSR.
// isX2=0: D = -dinv[n] * sum_e dinv[s]*S[s]            (X1 = -Ax(X0))
// isX2=1: D = -2*dinv[n]*sum_e dinv[s]*S[s] - A0[n]    (X2 = -2Ax(X1) - X0)
__device__ __forceinline__ void prop8(
    const float* __restrict__ S, int sstride, int soff,
    float* __restrict__ D,
    const float* __restrict__ A0, int aoff, int isX2,
    const unsigned short* __restrict__ csr_src,
    const int* __restrict__ csr_off,
    const float* __restrict__ sdinv,
    int tid)
{
    const int q = tid & 1;        // feature quad within slice
    const int n = tid >> 1;       // node (128 slots >= 100)
    if (n < P) {
        int kb = csr_off[n], ke = csr_off[n + 1];
        float ax = 0.f, ay = 0.f, az = 0.f, aw = 0.f;
        for (int k = kb; k < ke; k++) {
            int s = csr_src[k];
            float ws = sdinv[s];
            const float4 x = *(const float4*)&S[s * sstride + soff + q * 4];
            ax += ws * x.x; ay += ws * x.y; az += ws * x.z; aw += ws * x.w;
        }
        float dn = sdinv[n];
        float4 o;
        if (!isX2) {
            float m = -dn;
            o.x = m * ax; o.y = m * ay; o.z = m * az; o.w = m * aw;
        } else {
            float m = -2.f * dn;
            const float4 x0 = *(const float4*)&A0[n * ASTR + aoff + q * 4];
            o.x = m * ax - x0.x; o.y = m * ay - x0.y;
            o.z = m * az - x0.z; o.w = m * aw - x0.w;
        }
        *(float4*)&D[n * TSTR + q * 4] = o;
    }
}

// One ChebConv(K=3) layer: A (F cols) -> relu([X0|X1|X2]@W + b) -> A.
// Thread: cq4=(tid&15)*4 output cols; 7 uniform nodes n0=(tid>>4)*7 (pad rows
// 100..111 compute garbage that never escapes: gathers/pool only touch n<100).
template <int F>
__device__ __forceinline__ void cheb_layer(
    float* __restrict__ A, float* __restrict__ T1, float* __restrict__ T2,
    const unsigned short* __restrict__ csr_src,
    const int* __restrict__ csr_off,
    const float* __restrict__ sdinv,
    const float* __restrict__ W, const float* __restrict__ bias,
    int tid)
{
    const int cq4 = (tid & 15) * 4;
    const int n0  = (tid >> 4) * 7;

    float4 acc[7];
    const float4 bv = *(const float4*)&bias[cq4];
#pragma unroll
    for (int i = 0; i < 7; i++) acc[i] = bv;

    for (int cb = 0; cb < F; cb += 8) {
        prop8(A, ASTR, cb, T1, (const float*)0, 0, 0, csr_src, csr_off, sdinv, tid);
        __syncthreads();
        prop8(T1, TSTR, 0, T2, A, cb, 1, csr_src, csr_off, sdinv, tid);
        __syncthreads();

        // partial matmul over this 8-feature slice, 3 sections (X0, X1, X2)
        for (int sec = 0; sec < 3; sec++) {
            const float* xp; int xstr, xoff, wrow0;
            if (sec == 0)      { xp = A;  xstr = ASTR; xoff = cb; wrow0 = cb; }
            else if (sec == 1) { xp = T1; xstr = TSTR; xoff = 0;  wrow0 = F + cb; }
            else               { xp = T2; xstr = TSTR; xoff = 0;  wrow0 = 2 * F + cb; }
            for (int j4 = 0; j4 < 8; j4 += 4) {
                const float4 w0 = *(const float4*)&W[(wrow0 + j4 + 0) * HID + cq4];
                const float4 w1 = *(const float4*)&W[(wrow0 + j4 + 1) * HID + cq4];
                const float4 w2 = *(const float4*)&W[(wrow0 + j4 + 2) * HID + cq4];
                const float4 w3 = *(const float4*)&W[(wrow0 + j4 + 3) * HID + cq4];
                const float* xb = xp + n0 * xstr + xoff + j4;
#pragma unroll
                for (int i = 0; i < 7; i++) {
                    const float4 x = *(const float4*)&xb[i * xstr];
                    fma4(acc[i], x.x, w0); fma4(acc[i], x.y, w1);
                    fma4(acc[i], x.z, w2); fma4(acc[i], x.w, w3);
                }
            }
        }
        __syncthreads();   // T1/T2 (and A-slice) reads done before next overwrite
    }

    // H = relu(acc) -> A (pad rows written with don't-care values; no guard)
#pragma unroll
    for (int i = 0; i < 7; i++) {
        float4 o;
        o.x = fmaxf(acc[i].x, 0.f); o.y = fmaxf(acc[i].y, 0.f);
        o.z = fmaxf(acc[i].z, 0.f); o.w = fmaxf(acc[i].w, 0.f);
        *(float4*)&A[(n0 + i) * ASTR + cq4] = o;
    }
    __syncthreads();
}

__global__ __launch_bounds__(256, 4) void gnn_kernel(
    const float* __restrict__ feat,
    const int* __restrict__ src, const int* __restrict__ dst,
    const float* __restrict__ W1, const float* __restrict__ b1,
    const float* __restrict__ W2, const float* __restrict__ b2,
    const float* __restrict__ W3, const float* __restrict__ b3,
    const float* __restrict__ Wfc, const float* __restrict__ bfc,
    float* __restrict__ out)
{
    __shared__ __align__(16) float A[NPAD * ASTR];
    __shared__ __align__(16) float T1[NPAD * TSTR];
    __shared__ __align__(16) float T2[NPAD * TSTR];
    __shared__ unsigned short csr_src[EPG];
    __shared__ int   csr_off[P + 1];
    __shared__ float sdinv[P];

    const int g = blockIdx.x;
    const int tid = threadIdx.x;
    const int base = g * P;
    const int* srcg = src + g * EPG;
    const int* dstg = dst + g * EPG;

    int* deg = (int*)T1;   // aliased; consumed before layer 1
    int* cur = (int*)T2;   // aliased; consumed before layer 1

    // ---- degree count + feat load ----
    for (int i = tid; i < P; i += 256) deg[i] = 0;
    __syncthreads();
    for (int e = tid; e < EPG; e += 256) {
        int d = dstg[e] - base;
        atomicAdd(&deg[d], 1);
    }
    for (int i = tid; i < P * INF / 4; i += 256) {
        int n = i >> 2, fq = (i & 3) * 4;
        *(float4*)&A[n * ASTR + fq] = *(const float4*)&feat[(size_t)base * INF + i * 4];
    }
    __syncthreads();

    for (int i = tid; i < P; i += 256) {
        int dg = deg[i] > 1 ? deg[i] : 1;
        sdinv[i] = rsqrtf((float)dg);
    }
    // ---- prefix scan of degrees: serial by thread 0 (P=100, negligible) ----
    if (tid == 0) {
        int run = 0;
        csr_off[0] = 0;
        for (int i = 0; i < P; i++) { run += deg[i]; csr_off[i + 1] = run; }
    }
    __syncthreads();
    for (int i = tid; i < P; i += 256) cur[i] = csr_off[i];
    __syncthreads();
    // ---- CSR fill ----
    for (int e = tid; e < EPG; e += 256) {
        int s = srcg[e] - base;
        int d = dstg[e] - base;
        int pos = atomicAdd(&cur[d], 1);
        csr_src[pos] = (unsigned short)s;
    }
    __syncthreads();

    // ---- 3 ChebConv layers ----
    cheb_layer<INF>(A, T1, T2, csr_src, csr_off, sdinv, W1, b1, tid);
    cheb_layer<HID>(A, T1, T2, csr_src, csr_off, sdinv, W2, b2, tid);
    cheb_layer<HID>(A, T1, T2, csr_src, csr_off, sdinv, W3, b3, tid);

    // ---- mean pool + FC (T1 as scratch: 320 floats <= 896) ----
    {
        const int lane = tid & 63, w = tid >> 6;
        float s = 0.f;
        for (int n = w; n < P; n += 4) s += A[n * ASTR + lane];
        T1[w * 64 + lane] = s;
    }
    __syncthreads();
    if (tid < HID) {
        float hg = (T1[tid] + T1[64 + tid] + T1[128 + tid] + T1[192 + tid]) * (1.0f / P);
        T1[256 + tid] = hg;
    }
    __syncthreads();
    if (tid < NOUT) {
        float o = bfc[tid];
        for (int c = 0; c < HID; c++) o += T1[256 + c] * Wfc[c * NOUT + tid];
        out[g * NOUT + tid] = o;
    }
}

extern "C" void kernel_launch(void* const* d_in, const int* in_sizes, int n_in,
                              void* d_out, int out_size, void* d_ws, size_t ws_size,
                              hipStream_t stream)
{
    const float* feat = (const float*)d_in[0];
    const int*   src  = (const int*)d_in[1];
    const int*   dst  = (const int*)d_in[2];
    const float* W1  = (const float*)d_in[5];
    const float* b1  = (const float*)d_in[6];
    const float* W2  = (const float*)d_in[7];
    const float* b2  = (const float*)d_in[8];
    const float* W3  = (const float*)d_in[9];
    const float* b3  = (const float*)d_in[10];
    const float* Wfc = (const float*)d_in[11];
    const float* bfc = (const float*)d_in[12];
    float* out = (float*)d_out;

    gnn_kernel<<<NGRAPH, 256, 0, stream>>>(feat, src, dst,
                                           W1, b1, W2, b2, W3, b3, Wfc, bfc, out);
}